// Round 9
// baseline (139.615 us; speedup 1.0000x reference)
//
#include <hip/hip_runtime.h>
#include <hip/hip_bf16.h>
#include <cstdint>

#define BB 64
#define NN 512
#define MM 1024
#define DD 128

typedef __bf16 bf16x8 __attribute__((ext_vector_type(8)));
typedef float f32x4 __attribute__((ext_vector_type(4)));
typedef short s16x4 __attribute__((ext_vector_type(4)));

static __device__ __forceinline__ unsigned short f2bf(float f) {
    union { float f; unsigned int i; } v; v.f = f;
    unsigned int x = v.i;
    x += 0x7FFFu + ((x >> 16) & 1u);   // RNE
    return (unsigned short)(x >> 16);
}
// packed v_cvt_pk_bf16_f32: low = a, high = b
static __device__ __forceinline__ unsigned int f2bf2(float a, float b) {
    union { __hip_bfloat162 h; unsigned int u; } c;
    c.h = __float22bfloat162_rn(make_float2(a, b));
    return c.u;
}
// async global->LDS DMA, 16 B per lane, dest = wave-uniform base + lane*16
static __device__ __forceinline__ void async16(const void* g, void* l) {
    __builtin_amdgcn_global_load_lds(
        (const __attribute__((address_space(1))) void*)g,
        (__attribute__((address_space(3))) void*)l, 16, 0, 0);
}

// ---------- Kernel 1: merged projections, 6 tiles/block ----------------------
// Grid 256 = 1 block/CU (LDS 100352 B), zero dispatch tail, zero imbalance.
// Block i: V-tiles 4i..4i+3 (Vp swizzled-rows + VpT), C-tiles 2i..2i+1
// (Ucg + colsum).  Wu (x log2e) and Wv are converted ONCE per block into
// XOR-swizzled LDS (store = wcvt's proven pattern, read = rounds-4/5's proven
// pattern); X is double-buffered one tile ahead.
static __device__ __forceinline__ void loadx(
    float4 (&xv)[8], const float* __restrict__ base, long row0,
    int wave, int n16, int q)
{
    const float* xrow = base + (row0 + wave * 16 + n16) * DD + q * 8;
    #pragma unroll
    for (int kk = 0; kk < 4; ++kk) {
        xv[2 * kk]     = *(const float4*)(xrow + kk * 32);
        xv[2 * kk + 1] = *(const float4*)(xrow + kk * 32 + 4);
    }
}

template <bool ISC>
static __device__ __forceinline__ void proj_tile(
    const float4 (&xv)[8],
    const unsigned short* Ws,                 // swizzled W in LDS
    const float* __restrict__ bias,
    long row0,
    unsigned short* Ys, unsigned short* Ts,
    unsigned short* __restrict__ Y, unsigned short* __restrict__ YT,
    unsigned short* __restrict__ Ucg, float* __restrict__ colsum,
    int t, int wave, int n16, int q)
{
    const float bsc = ISC ? 1.44269504088896f : 1.0f;
    f32x4 acc[8];
    #pragma unroll
    for (int j = 0; j < 8; ++j) acc[j] = {0.f, 0.f, 0.f, 0.f};

    #pragma unroll
    for (int kk = 0; kk < 4; ++kk) {
        float4 x0 = xv[2 * kk], x1 = xv[2 * kk + 1];
        union { bf16x8 v; unsigned int u[4]; } a;
        a.u[0] = f2bf2(x0.x, x0.y); a.u[1] = f2bf2(x0.z, x0.w);
        a.u[2] = f2bf2(x1.x, x1.y); a.u[3] = f2bf2(x1.z, x1.w);
        #pragma unroll
        for (int j = 0; j < 8; ++j) {
            bf16x8 b = *(const bf16x8*)&Ws[(j * 16 + n16) * 128
                                           + (((q + 4 * kk) ^ (n16 & 7)) << 3)];
            acc[j] = __builtin_amdgcn_mfma_f32_16x16x32_bf16(a.v, b, acc[j], 0, 0, 0);
        }
    }

    unsigned short yb[8][4];
    float colp[8];
    #pragma unroll
    for (int j = 0; j < 8; ++j) {
        const float bv = bias[j * 16 + n16] * bsc;
        float y[4], s = 0.f;
        #pragma unroll
        for (int r = 0; r < 4; ++r) {
            float v = acc[j][r] + bv;
            v = v > 0.f ? v : 0.f;
            y[r] = v;
            s += v;
        }
        colp[j] = s;
        uint2 u = { f2bf2(y[0], y[1]), f2bf2(y[2], y[3]) };
        *(uint2*)&yb[j][0] = u;
    }

    if (!ISC) {
        #pragma unroll
        for (int j = 0; j < 8; ++j) {
            const int e = j * 16 + n16;
            const int ehi = e >> 3, elo = e & 7;
            #pragma unroll
            for (int r = 0; r < 4; ++r) {
                int row = wave * 16 + q * 4 + r;
                // PRE-SWIZZLED row store: attn DMAs this row linearly to LDS
                Ys[row * 128 + ((ehi ^ (row & 7)) << 3) + elo] = yb[j][r];
            }
            *(uint2*)&Ts[e * 72 + wave * 16 + q * 4] = *(uint2*)&yb[j][0];
        }
        __syncthreads();                       // Ys/Ts complete
        uint4* dstY = (uint4*)(Y + row0 * DD);
        uint4* dstT = (uint4*)(YT + row0 * 128);   // == tile_index * 8192
        #pragma unroll
        for (int i = 0; i < 4; ++i) {
            int idx = i * 256 + t;
            dstY[idx] = ((const uint4*)Ys)[idx];
            int e = idx >> 3, m = (idx & 7) * 8;
            dstT[idx] = *(const uint4*)&Ts[e * 72 + m];
        }
        __syncthreads();                       // Ys/Ts free for next tile
    } else {
        // column-sum: colp[j] covers rows (q,r) for col j*16+n16; reduce q
        #pragma unroll
        for (int j = 0; j < 8; ++j) {
            colp[j] += __shfl_xor(colp[j], 16);
            colp[j] += __shfl_xor(colp[j], 32);
        }
        float* cs = (float*)Ts;                // 512 floats
        if (q == 0) {
            #pragma unroll
            for (int j = 0; j < 8; ++j)
                cs[wave * 128 + j * 16 + n16] = colp[j];
        }
        #pragma unroll
        for (int j = 0; j < 8; ++j) {
            const int e = j * 16 + n16;
            #pragma unroll
            for (int r = 0; r < 4; ++r)
                Ys[(wave * 16 + q * 4 + r) * 128 + e] = yb[j][r];
        }
        __syncthreads();                       // Ys + cs complete
        uint4* dstU = (uint4*)(Ucg + row0 * DD);
        #pragma unroll
        for (int i = 0; i < 4; ++i) {
            int idx = i * 256 + t;
            dstU[idx] = ((const uint4*)Ys)[idx];
        }
        if (t < 128) {
            int c = (int)(row0 >> 6);
            colsum[(long)c * DD + t] = cs[t] + cs[128 + t] + cs[256 + t] + cs[384 + t];
        }
        __syncthreads();                       // Ys/Ts free for next tile
    }
}

__global__ __launch_bounds__(256, 2) void proj_kernel(
    const float* __restrict__ hp,
    const float* __restrict__ hc,
    const float* __restrict__ Wu,
    const float* __restrict__ Wv,
    const float* __restrict__ Ub,
    const float* __restrict__ Vb,
    unsigned short* __restrict__ Y,           // Vp  (B,16,64,128) swizzled rows
    unsigned short* __restrict__ YT,          // VpT (B,16,128,64)
    unsigned short* __restrict__ Ucg,         // (B*512,128) bf16 row-major
    float* __restrict__ colsum)               // (B*8,128) f32
{
    __shared__ __align__(16) unsigned short S[50176];   // 100352 B
    unsigned short* Wvs = S;            // 16384 shorts, swizzled
    unsigned short* Wus = S + 16384;    // 16384 shorts, swizzled + log2e
    unsigned short* Ys  = S + 32768;    // 8192 shorts
    unsigned short* Ts  = S + 40960;    // 9216 shorts

    const int t = threadIdx.x;
    const int lane = t & 63;
    const int wave = t >> 6;
    const int n16 = lane & 15, q = lane >> 4;
    const int blk = blockIdx.x;               // 0..255

    const long v0 = (long)blk * 4 * 64;       // first V row (of B*M)
    const long c0 = (long)blk * 2 * 64;       // first C row (of B*N)

    float4 xa[8], xb[8];
    loadx(xa, hp, v0, wave, n16, q);          // V-tile 0 X first (overlaps W)

    // stage Wv -> swizzled LDS
    {
        const float4* Wg = (const float4*)Wv;
        #pragma unroll
        for (int i = 0; i < 16; ++i) {
            int idx = i * 256 + t;
            float4 v = Wg[idx];
            int off = idx * 4, r = off >> 7, c = off & 127;
            uint2 u = { f2bf2(v.x, v.y), f2bf2(v.z, v.w) };
            *(uint2*)&Wvs[r * 128 + (((c >> 3) ^ (r & 7)) << 3) + (c & 7)] = u;
        }
    }
    // stage Wu * log2(e) -> swizzled LDS
    {
        const float4* Wg = (const float4*)Wu;
        const float s = 1.44269504088896f;
        #pragma unroll
        for (int i = 0; i < 16; ++i) {
            int idx = i * 256 + t;
            float4 v = Wg[idx];
            int off = idx * 4, r = off >> 7, c = off & 127;
            uint2 u = { f2bf2(v.x * s, v.y * s), f2bf2(v.z * s, v.w * s) };
            *(uint2*)&Wus[r * 128 + (((c >> 3) ^ (r & 7)) << 3) + (c & 7)] = u;
        }
    }
    __syncthreads();

    loadx(xb, hp, v0 + 64, wave, n16, q);
    proj_tile<false>(xa, Wvs, Vb, v0,       Ys, Ts, Y, YT, Ucg, colsum, t, wave, n16, q);
    loadx(xa, hp, v0 + 128, wave, n16, q);
    proj_tile<false>(xb, Wvs, Vb, v0 + 64,  Ys, Ts, Y, YT, Ucg, colsum, t, wave, n16, q);
    loadx(xb, hp, v0 + 192, wave, n16, q);
    proj_tile<false>(xa, Wvs, Vb, v0 + 128, Ys, Ts, Y, YT, Ucg, colsum, t, wave, n16, q);
    loadx(xa, hc, c0, wave, n16, q);
    proj_tile<false>(xb, Wvs, Vb, v0 + 192, Ys, Ts, Y, YT, Ucg, colsum, t, wave, n16, q);
    loadx(xb, hc, c0 + 64, wave, n16, q);
    proj_tile<true>(xa, Wus, Ub, c0,        Ys, Ts, Y, YT, Ucg, colsum, t, wave, n16, q);
    proj_tile<true>(xb, Wus, Ub, c0 + 64,   Ys, Ts, Y, YT, Ucg, colsum, t, wave, n16, q);
}

// ---------- Kernel 2: EXCHANGE-FREE bilinear attention (round-8, verified) ---
__global__ __launch_bounds__(256, 2) void attn_kernel(
    const unsigned short* __restrict__ Ucg,   // (B*512,128) bf16, pre-scaled
    const unsigned short* __restrict__ Vp,    // (B,16,64,128) swizzled rows
    const unsigned short* __restrict__ VpT,   // (B,16,128,64) bf16 tiled
    float* __restrict__ part)                 // (B*8,128) fp32
{
    __shared__ __align__(16) unsigned short smem[32768];   // 65536 B

    const int t = threadIdx.x;
    const int lane = t & 63;
    const int wave = t >> 6;
    const int n16 = lane & 15, q = lane >> 4;

    const int id = blockIdx.x;
    const int xcd = id & 7;
    const int slot = id >> 3;
    const int b = xcd * 8 + (slot >> 3);
    const int nt = slot & 7;

    const unsigned short* vpb = Vp + (long)b * MM * DD;    // 16 tiles of 8192
    const unsigned short* vtb = VpT + (long)b * MM * DD;
    const unsigned short* ucb = Ucg + ((long)b * NN + nt * 64) * DD;

    // B-frags: the wave's own 16 n-rows of Uc (16 VGPR, live all iterations)
    bf16x8 Bn[4];
    #pragma unroll
    for (int kk = 0; kk < 4; ++kk)
        Bn[kk] = *(const bf16x8*)&ucb[(wave * 16 + n16) * 128 + kk * 32 + q * 8];

    // Prologue: DMA tile 0 (Vp linear — global pre-swizzled; VpT src-swizzled)
    {
        #pragma unroll
        for (int i = 0; i < 4; ++i) {
            int L = wave * 256 + i * 64 + lane;
            async16(vpb + L * 8, smem + wave * 2048 + i * 512);
        }
        #pragma unroll
        for (int i = 0; i < 4; ++i) {
            int L = wave * 256 + i * 64 + lane;
            int r = L >> 3, sc = L & 7, c = sc ^ (r & 7);
            async16(vtb + r * 64 + c * 8, smem + 16384 + wave * 2048 + i * 512);
        }
    }
    asm volatile("s_waitcnt vmcnt(0) lgkmcnt(0)" ::: "memory");
    __builtin_amdgcn_s_barrier();
    __builtin_amdgcn_sched_barrier(0);

    f32x4 O[8];
    #pragma unroll
    for (int j = 0; j < 8; ++j) O[j] = {0.f, 0.f, 0.f, 0.f};
    float lsum = 0.f;

    #pragma unroll 1
    for (int mt = 0; mt < 16; ++mt) {
        const unsigned short* V  = (mt & 1) ? smem + 8192  : smem;
        const unsigned short* VT = (mt & 1) ? smem + 24576 : smem + 16384;
        // DMA tile mt+1 into the other parity (safe: that parity's readers
        // drained at barrier(mt-1); we are past it)
        if (mt < 15) {
            const unsigned short* sv = vpb + (mt + 1) * 8192;
            const unsigned short* st = vtb + (mt + 1) * 8192;
            unsigned short* dv = ((mt & 1) ? smem : smem + 8192) + wave * 2048;
            unsigned short* dt = ((mt & 1) ? smem + 16384 : smem + 24576) + wave * 2048;
            #pragma unroll
            for (int i = 0; i < 4; ++i) {
                int L = wave * 256 + i * 64 + lane;
                async16(sv + L * 8, dv + i * 512);
            }
            #pragma unroll
            for (int i = 0; i < 4; ++i) {
                int L = wave * 256 + i * 64 + lane;
                int r = L >> 3, sc = L & 7, c = sc ^ (r & 7);
                async16(st + r * 64 + c * 8, dt + i * 512);
            }
        }
        __builtin_amdgcn_sched_barrier(0);

        // QK: S[mtile] over all 64 m, own 16 n.  A from swizzled LDS rows.
        f32x4 S[4];
        #pragma unroll
        for (int j = 0; j < 4; ++j) S[j] = {0.f, 0.f, 0.f, 0.f};
        __builtin_amdgcn_s_setprio(1);
        #pragma unroll
        for (int mtile = 0; mtile < 4; ++mtile) {
            const int m = mtile * 16 + n16;
            #pragma unroll
            for (int kk = 0; kk < 4; ++kk) {
                bf16x8 a = *(const bf16x8*)&V[m * 128 + (((kk * 4 + q) ^ (m & 7)) << 3)];
                S[mtile] = __builtin_amdgcn_mfma_f32_16x16x32_bf16(a, Bn[kk], S[mtile], 0, 0, 0);
            }
        }
        __builtin_amdgcn_s_setprio(0);

        // p = exp2(S); pack DIRECTLY into K=16 PV A-frags (lane-local!)
        s16x4 av[4];
        #pragma unroll
        for (int j = 0; j < 4; ++j) {
            float p0 = __builtin_exp2f(S[j][0]);
            float p1 = __builtin_exp2f(S[j][1]);
            float p2 = __builtin_exp2f(S[j][2]);
            float p3 = __builtin_exp2f(S[j][3]);
            lsum += (p0 + p1) + (p2 + p3);
            union { unsigned int u[2]; s16x4 v; } pk;
            pk.u[0] = f2bf2(p0, p1); pk.u[1] = f2bf2(p2, p3);
            av[j] = pk.v;
        }

        // PV: O[n-own][d] += P[n][m-chunk] * V[m-chunk][d], K=16 per mtile.
        // B-frag: VT[d = dj*16+n16][m = mtile*16 + q*4 .. +3] (b64, swizzled).
        __builtin_amdgcn_s_setprio(1);
        #pragma unroll
        for (int mtile = 0; mtile < 4; ++mtile) {
            #pragma unroll
            for (int dj = 0; dj < 8; ++dj) {
                const int d = dj * 16 + n16;
                s16x4 bv = *(const s16x4*)&VT[d * 64
                    + (((mtile * 2 + (q >> 1)) ^ (d & 7)) << 3) + ((q & 1) << 2)];
                O[dj] = __builtin_amdgcn_mfma_f32_16x16x16bf16_1k(av[mtile], bv, O[dj], 0, 0, 0);
            }
        }
        __builtin_amdgcn_s_setprio(0);

        // publish: own ds_reads done + own DMA landed; barrier releases bufs
        asm volatile("s_waitcnt vmcnt(0) lgkmcnt(0)" ::: "memory");
        __builtin_amdgcn_s_barrier();
        __builtin_amdgcn_sched_barrier(0);
    }

    // ---- Epilogue ----
    // lsum: n = w*16+n16 is lane-local; reduce over q -> full row sum
    lsum += __shfl_xor(lsum, 16);
    lsum += __shfl_xor(lsum, 32);
    float* scr  = (float*)smem;          // buffers dead after final barrier
    float* invw = scr + wave * 16;       // per-wave 16 floats (wave-private)
    if (lane < 16) invw[n16] = 1.0f / lsum;
    // wave-internal ds_write->ds_read: in-order, compiler inserts lgkmcnt
    float iv[4];
    #pragma unroll
    for (int r = 0; r < 4; ++r) iv[r] = invw[q * 4 + r];

    float* red = scr + 64;               // 512 floats
    #pragma unroll
    for (int dj = 0; dj < 8; ++dj) {
        float s = O[dj][0] * iv[0] + O[dj][1] * iv[1]
                + O[dj][2] * iv[2] + O[dj][3] * iv[3];
        s += __shfl_xor(s, 16);
        s += __shfl_xor(s, 32);
        if (q == 0)
            red[wave * 128 + dj * 16 + n16] = s;
    }
    __syncthreads();
    if (t < 128) {
        float tot = red[t] + red[128 + t] + red[256 + t] + red[384 + t];
        part[(long)(b * 8 + nt) * DD + t] = tot;
    }
}

// ---------- Kernel 3: out = (Sigma part + RLN2*Sigma colsum) * q / N ---------
__global__ __launch_bounds__(256) void finalize_kernel(
    const float* __restrict__ part, const float* __restrict__ colsum,
    const float* __restrict__ qv, float* __restrict__ out)
{
    int i = blockIdx.x * 256 + threadIdx.x;     // 8192
    int b = i >> 7, d = i & 127;
    const float* p  = part   + (long)b * 8 * DD + d;
    const float* cs = colsum + (long)b * 8 * DD + d;
    float s = 0.f, u = 0.f;
    #pragma unroll
    for (int nt = 0; nt < 8; ++nt) { s += p[nt * DD]; u += cs[nt * DD]; }
    out[i] = (s + u * 0.69314718055994531f) * qv[d] * (1.0f / (float)NN);
}

extern "C" void kernel_launch(void* const* d_in, const int* in_sizes, int n_in,
                              void* d_out, int out_size, void* d_ws, size_t ws_size,
                              hipStream_t stream) {
    const float* h_c = (const float*)d_in[0];
    const float* h_p = (const float*)d_in[1];
    const float* U_w = (const float*)d_in[2];
    const float* U_b = (const float*)d_in[3];
    const float* V_w = (const float*)d_in[4];
    const float* V_b = (const float*)d_in[5];
    const float* qv  = (const float*)d_in[6];
    float* out = (float*)d_out;

    unsigned short* Vp  = (unsigned short*)d_ws;                 // (B,16,64,128) bf16 swz
    unsigned short* VpT = Vp + (size_t)BB * MM * DD;             // (B,16,128,64) bf16
    unsigned short* Ucg = VpT + (size_t)BB * MM * DD;            // (B*512,128) bf16
    float* part   = (float*)(Ucg + (size_t)BB * NN * DD);        // (B*8,128) fp32
    float* colsum = part + (size_t)BB * 8 * DD;                  // (B*8,128) fp32

    proj_kernel<<<256, 256, 0, stream>>>(
        h_p, h_c, U_w, V_w, U_b, V_b, Vp, VpT, Ucg, colsum);
    attn_kernel<<<512, 256, 0, stream>>>(Ucg, Vp, VpT, part);
    finalize_kernel<<<32, 256, 0, stream>>>(part, colsum, qv, out);
}